// Round 3
// baseline (323.755 us; speedup 1.0000x reference)
//
#include <hip/hip_runtime.h>
#include <math.h>

#define HW 1024
#define Hd 32
#define Wd 32
#define Bn 8
#define Cc 256

// ---------------- Kernel T: transpose x[b][c][hw] -> xt[b*1024+hw][c] -------
__global__ __launch_bounds__(256) void kT(const float* __restrict__ x,
                                          float* __restrict__ xt) {
    __shared__ float tile[64][65];
    int bid = blockIdx.x;                 // 8 b x 4 ct x 16 ht = 512
    int b = bid >> 6, ct = (bid >> 4) & 3, ht = bid & 15;
    int c0 = ct * 64, hw0 = ht * 64;
    int tr = threadIdx.x >> 6, tc = threadIdx.x & 63;
    const float* xb = x + ((size_t)b * 256 + c0) * 1024 + hw0;
    #pragma unroll
    for (int k = 0; k < 16; ++k) {
        int c = tr + k * 4;
        tile[c][tc] = xb[(size_t)c * 1024 + tc];
    }
    __syncthreads();
    float* xo = xt + ((size_t)b * 1024 + hw0) * 256 + c0;
    #pragma unroll
    for (int k = 0; k < 16; ++k) {
        int hwl = tr + k * 4;
        xo[(size_t)hwl * 256 + tc] = tile[tc][hwl];
    }
}

// ---------------- Kernel A: primary caps (1x1 conv + BN + SiLU + squash) ----
// 4 waves/block, 4 pixels/wave (16/block). weights staged+transposed in LDS.
__global__ __launch_bounds__(256) void kA(const float* __restrict__ xt,
        const float* __restrict__ pw, const float* __restrict__ gamma,
        const float* __restrict__ beta, const float* __restrict__ mean,
        const float* __restrict__ var, float* __restrict__ child_t) {
    __shared__ float wl[16384];           // [c4][o][e] layout, 64 KB
    for (int i = threadIdx.x; i < 16384; i += 256) {
        int o = i >> 8, c = i & 255;
        wl[((c >> 2) * 64 + o) * 4 + (c & 3)] = pw[i];
    }
    __syncthreads();
    int wid = threadIdx.x >> 6, lane = threadIdx.x & 63;
    int o = lane;
    double scale = (double)gamma[o] / sqrt((double)var[o] + 1e-5);
    double mn = (double)mean[o], bt = (double)beta[o];
    const float4* wl4 = reinterpret_cast<const float4*>(wl);
    #pragma unroll
    for (int pp = 0; pp < 4; pp += 2) {   // 2 pixels share each weight pass
        int m0 = (blockIdx.x * 4 + wid) * 4 + pp;
        const float4* xa = reinterpret_cast<const float4*>(xt + (size_t)m0 * 256);
        const float4* xb = reinterpret_cast<const float4*>(xt + (size_t)(m0 + 1) * 256);
        double a0 = 0.0, a1 = 0.0;
        #pragma unroll 8
        for (int c4 = 0; c4 < 64; ++c4) {
            float4 wv = wl4[c4 * 64 + lane];
            float4 v0 = xa[c4], v1 = xb[c4];
            a0 += (double)wv.x * v0.x + (double)wv.y * v0.y +
                  (double)wv.z * v0.z + (double)wv.w * v0.w;
            a1 += (double)wv.x * v1.x + (double)wv.y * v1.y +
                  (double)wv.z * v1.z + (double)wv.w * v1.w;
        }
        #pragma unroll
        for (int e = 0; e < 2; ++e) {
            double acc = e ? a1 : a0;
            double t = (acc - mn) * scale + bt;
            double s = t / (1.0 + exp(-t));          // SiLU
            double sq = s * s;                        // squash over 8-lane group
            sq += __shfl_xor(sq, 1);
            sq += __shfl_xor(sq, 2);
            sq += __shfl_xor(sq, 4);
            double f = (sq / (1.0 + sq)) / sqrt(sq + 1e-7);
            child_t[(size_t)(m0 + e) * 64 + o] = (float)(s * f);
        }
    }
}

// ---------------- Kernel C2: transpose conv weights to [tap][oc][c] ---------
__global__ void kC2(const float* __restrict__ ow, float* __restrict__ wt2) {
    int t = blockIdx.x * 256 + threadIdx.x;   // 18432
    int c = t & 255, oc = (t >> 8) & 7, tap = t >> 11;
    wt2[t] = ow[(oc * 256 + c) * 9 + tap];
}

// ---------------- Kernel B: 3x3 offset conv + tanh -> sampling grids --------
// 4 waves/block, 4 pixels/wave. lane = 4-channel chunk. taps 0..7 in LDS.
__global__ __launch_bounds__(256) void kB(const float* __restrict__ xt,
        const float* __restrict__ wt2, const float* __restrict__ ob,
        float* __restrict__ grids) {
    __shared__ float wl[16384];               // 8 taps x 8 oc x 256 c = 64 KB
    for (int i = threadIdx.x; i < 4096; i += 256)
        reinterpret_cast<float4*>(wl)[i] =
            reinterpret_cast<const float4*>(wt2)[i];
    __syncthreads();

    int wid = threadIdx.x >> 6, lane = threadIdx.x & 63;
    for (int p = 0; p < 4; ++p) {
        int m = (blockIdx.x * 4 + wid) * 4 + p;
        int b = m >> 10, hw = m & 1023;
        int yy = hw >> 5, xx = hw & 31;
        const float* xb = xt + (size_t)b * HW * 256;

        float acc[8] = {0.f, 0.f, 0.f, 0.f, 0.f, 0.f, 0.f, 0.f};
        #pragma unroll
        for (int tap = 0; tap < 9; ++tap) {
            int ky = tap / 3 - 1, kx = tap % 3 - 1;
            int yq = yy + ky, xq = xx + kx;
            if (yq < 0 || yq > Hd - 1 || xq < 0 || xq > Wd - 1) continue;
            float4 xv = *reinterpret_cast<const float4*>(
                xb + (size_t)(yq * Wd + xq) * 256 + lane * 4);
            #pragma unroll
            for (int oc = 0; oc < 8; ++oc) {
                float4 wv = (tap < 8)
                    ? *reinterpret_cast<const float4*>(wl + (tap * 8 + oc) * 256 + lane * 4)
                    : *reinterpret_cast<const float4*>(wt2 + (8 * 8 + oc) * 256 + lane * 4);
                acc[oc] += xv.x * wv.x + xv.y * wv.y + xv.z * wv.z + xv.w * wv.w;
            }
        }
        #pragma unroll
        for (int mk = 1; mk <= 32; mk <<= 1)
            #pragma unroll
            for (int oc = 0; oc < 8; ++oc)
                acc[oc] += __shfl_xor(acc[oc], mk);

        if (lane < 8) {
            double t = tanh((double)acc[lane] + (double)ob[lane]);
            int coord = lane & 1, si = lane >> 1;
            double base = coord ? (-1.0 + 2.0 * (double)yy / 31.0)
                                : (-1.0 + 2.0 * (double)xx / 31.0);
            grids[(size_t)m * 8 + si * 2 + coord] = (float)(base + t / 15.5);
        }
    }
}

// ---------------- Kernel C: reorder routing_W for coalesced float4 reads ----
// lane l <-> (n = l>>1, half = l&1); chunk j = o_loc*128 + d*8 + i (512 floats)
__global__ void kC(const float* __restrict__ rw, float* __restrict__ wt) {
    int t = blockIdx.x * 256 + threadIdx.x;  // 32768
    int e = t & 3, l = (t >> 2) & 63, j4 = t >> 8;
    int n = l >> 1, half = l & 1;
    wt[t] = rw[n * 1024 + half * 512 + j4 * 4 + e];
}

// ---------------- Kernel D: bilinear sample + u_hat + dynamic routing -------
// 8 waves/block, 4 pixels/wave, grid 256 (1 block/CU). wt in 128 KB dyn LDS.
// lane <-> (n = lane>>1, half = lane&1). u_hat in regs u[4][16].
__global__ __launch_bounds__(512, 1) void kD(const float* __restrict__ child_t,
        const float* __restrict__ grids, const float* __restrict__ wt,
        float* __restrict__ out) {
    extern __shared__ float wl[];             // 32768 floats = 128 KB
    {
        const float4* src = reinterpret_cast<const float4*>(wt);
        float4* dst = reinterpret_cast<float4*>(wl);
        for (int i = threadIdx.x; i < 8192; i += 512) dst[i] = src[i];
    }
    __syncthreads();
    int wid = threadIdx.x >> 6, lane = threadIdx.x & 63;
    int n = lane >> 1, half = lane & 1;
    int si = n >> 3, ch = n & 7;
    const float4* wl4 = reinterpret_cast<const float4*>(wl) + lane;

    for (int p = 0; p < 4; ++p) {
        int m = (blockIdx.x * 8 + wid) * 4 + p;   // pixel
        int b = m >> 10, hw = m & 1023;

        // ---- bilinear sampling (align_corners=True, zeros padding), f32 ----
        float gx = grids[m * 8 + si * 2 + 0];
        float gy = grids[m * 8 + si * 2 + 1];
        float xf = (gx + 1.f) * 0.5f * 31.f;
        float yf = (gy + 1.f) * 0.5f * 31.f;
        float x0 = floorf(xf), y0 = floorf(yf);
        float wx1 = xf - x0, wx0 = 1.f - wx1;
        float wy1 = yf - y0, wy0 = 1.f - wy1;
        float sf[8] = {0.f, 0.f, 0.f, 0.f, 0.f, 0.f, 0.f, 0.f};
        const float* cb = child_t + (size_t)b * HW * 64 + ch * 8;
        #pragma unroll
        for (int cy = 0; cy < 2; ++cy) {
            float yq = y0 + (float)cy;
            bool vy = (yq >= 0.f) && (yq <= 31.f);
            float wy = cy ? wy1 : wy0;
            #pragma unroll
            for (int cx = 0; cx < 2; ++cx) {
                float xq = x0 + (float)cx;
                bool ok = vy && (xq >= 0.f) && (xq <= 31.f);
                if (!ok) continue;
                float w = wy * (cx ? wx1 : wx0);
                const float* cp = cb + (size_t)((int)yq * Wd + (int)xq) * 64;
                float4 v0 = *reinterpret_cast<const float4*>(cp);
                float4 v1 = *reinterpret_cast<const float4*>(cp + 4);
                sf[0] += w * v0.x; sf[1] += w * v0.y;
                sf[2] += w * v0.z; sf[3] += w * v0.w;
                sf[4] += w * v1.x; sf[5] += w * v1.y;
                sf[6] += w * v1.z; sf[7] += w * v1.w;
            }
        }

        // ---- u_hat = W[n] . samp  (dense ds_read_b128) ----
        float u[4][16];
        #pragma unroll
        for (int j4 = 0; j4 < 128; ++j4) {
            float4 wv = wl4[j4 * 64];
            int o_loc = j4 >> 5, d = (j4 >> 1) & 15, i4 = (j4 & 1) * 4;
            float val = wv.x * sf[i4] + wv.y * sf[i4 + 1] +
                        wv.z * sf[i4 + 2] + wv.w * sf[i4 + 3];
            if ((j4 & 1) == 0) u[o_loc][d] = val; else u[o_loc][d] += val;
        }

        // ---- dynamic routing (3 iters), all in registers ----
        float bl[4] = {0.f, 0.f, 0.f, 0.f};
        float vv[4][16];
        #pragma unroll
        for (int it = 0; it < 3; ++it) {
            float mx = fmaxf(fmaxf(bl[0], bl[1]), fmaxf(bl[2], bl[3]));
            mx = fmaxf(mx, __shfl_xor(mx, 1));
            float ex[4], ssum = 0.f;
            #pragma unroll
            for (int k = 0; k < 4; ++k) { ex[k] = expf(bl[k] - mx); ssum += ex[k]; }
            ssum += __shfl_xor(ssum, 1);
            float c[4];
            #pragma unroll
            for (int k = 0; k < 4; ++k) c[k] = ex[k] / ssum;
            #pragma unroll
            for (int o = 0; o < 4; ++o)
                #pragma unroll
                for (int d = 0; d < 16; ++d) vv[o][d] = c[o] * u[o][d];
            #pragma unroll
            for (int mk = 2; mk <= 32; mk <<= 1)
                #pragma unroll
                for (int o = 0; o < 4; ++o)
                    #pragma unroll
                    for (int d = 0; d < 16; ++d)
                        vv[o][d] += __shfl_xor(vv[o][d], mk);
            #pragma unroll
            for (int o = 0; o < 4; ++o) {
                float sq = 0.f;
                #pragma unroll
                for (int d = 0; d < 16; ++d) sq += vv[o][d] * vv[o][d];
                float f = (sq / (1.f + sq)) / sqrtf(sq + 1e-7f);
                #pragma unroll
                for (int d = 0; d < 16; ++d) vv[o][d] *= f;
            }
            if (it < 2) {
                #pragma unroll
                for (int o = 0; o < 4; ++o) {
                    float agg = 0.f;
                    #pragma unroll
                    for (int d = 0; d < 16; ++d) agg += u[o][d] * vv[o][d];
                    bl[o] += agg;
                }
            }
        }

        // ---- scatter v to out[b][(half*4+o_loc)*16 + d][hw] ----
        int o_loc = n >> 3;
        int och = half * 4 + o_loc;
        #pragma unroll
        for (int e = 0; e < 2; ++e) {
            int d = (n & 7) * 2 + e;
            out[((size_t)b * 128 + och * 16 + d) * HW + hw] = vv[o_loc][d];
        }
    }
}

extern "C" void kernel_launch(void* const* d_in, const int* in_sizes, int n_in,
                              void* d_out, int out_size, void* d_ws, size_t ws_size,
                              hipStream_t stream) {
    const float* x     = (const float*)d_in[0];
    const float* pw    = (const float*)d_in[1];
    const float* gamma = (const float*)d_in[2];
    const float* beta  = (const float*)d_in[3];
    const float* mean  = (const float*)d_in[4];
    const float* var   = (const float*)d_in[5];
    const float* ow    = (const float*)d_in[6];
    const float* ob    = (const float*)d_in[7];
    const float* rw    = (const float*)d_in[8];
    float* out = (float*)d_out;
    char* ws = (char*)d_ws;
    float* child_t = (float*)ws;                    // 8192*64*4 = 2 MiB
    float* grids   = (float*)(ws + 2097152);        // 8192*8*4  = 256 KiB
    float* wt      = (float*)(ws + 2359296);        // 32768*4   = 128 KiB
    float* xt      = (float*)(ws + 2490368);        // 8192*256*4 = 8 MiB
    float* wt2     = (float*)(ws + 10878976);       // 18432*4   = 72 KiB

    hipLaunchKernelGGL(kT, dim3(512), dim3(256), 0, stream, x, xt);
    hipLaunchKernelGGL(kC2, dim3(72), dim3(256), 0, stream, ow, wt2);
    hipLaunchKernelGGL(kC, dim3(128), dim3(256), 0, stream, rw, wt);
    hipLaunchKernelGGL(kA, dim3(512), dim3(256), 0, stream,
                       xt, pw, gamma, beta, mean, var, child_t);
    hipLaunchKernelGGL(kB, dim3(512), dim3(256), 0, stream, xt, wt2, ob, grids);
    hipLaunchKernelGGL(kD, dim3(256), dim3(512), 131072, stream,
                       child_t, grids, wt, out);
}

// Round 4
// 288.648 us; speedup vs baseline: 1.1216x; 1.1216x over previous
//
#include <hip/hip_runtime.h>
#include <math.h>

#define HW 1024
#define Hd 32
#define Wd 32
#define Bn 8
#define Cc 256

// ---------------- Kernel T: transpose x[b][c][hw] -> xt[b*1024+hw][c] -------
__global__ __launch_bounds__(256) void kT(const float* __restrict__ x,
                                          float* __restrict__ xt) {
    __shared__ float tile[64][65];
    int bid = blockIdx.x;                 // 8 b x 4 ct x 16 ht = 512
    int b = bid >> 6, ct = (bid >> 4) & 3, ht = bid & 15;
    int c0 = ct * 64, hw0 = ht * 64;
    int tr = threadIdx.x >> 6, tc = threadIdx.x & 63;
    const float* xb = x + ((size_t)b * 256 + c0) * 1024 + hw0;
    #pragma unroll
    for (int k = 0; k < 16; ++k) {
        int c = tr + k * 4;
        tile[c][tc] = xb[(size_t)c * 1024 + tc];
    }
    __syncthreads();
    float* xo = xt + ((size_t)b * 1024 + hw0) * 256 + c0;
    #pragma unroll
    for (int k = 0; k < 16; ++k) {
        int hwl = tr + k * 4;
        xo[(size_t)hwl * 256 + tc] = tile[tc][hwl];
    }
}

// ---------------- Kernel A: primary caps (1x1 conv + BN + SiLU + squash) ----
// 4 waves/block, 4 pixels/wave (16/block). weights staged+transposed in LDS.
__global__ __launch_bounds__(256) void kA(const float* __restrict__ xt,
        const float* __restrict__ pw, const float* __restrict__ gamma,
        const float* __restrict__ beta, const float* __restrict__ mean,
        const float* __restrict__ var, float* __restrict__ child_t) {
    __shared__ float wl[16384];           // [c4][o][e] layout, 64 KB
    for (int i = threadIdx.x; i < 16384; i += 256) {
        int o = i >> 8, c = i & 255;
        wl[((c >> 2) * 64 + o) * 4 + (c & 3)] = pw[i];
    }
    __syncthreads();
    int wid = threadIdx.x >> 6, lane = threadIdx.x & 63;
    int o = lane;
    double scale = (double)gamma[o] / sqrt((double)var[o] + 1e-5);
    double mn = (double)mean[o], bt = (double)beta[o];
    const float4* wl4 = reinterpret_cast<const float4*>(wl);
    #pragma unroll
    for (int pp = 0; pp < 4; pp += 2) {   // 2 pixels share each weight pass
        int m0 = (blockIdx.x * 4 + wid) * 4 + pp;
        const float4* xa = reinterpret_cast<const float4*>(xt + (size_t)m0 * 256);
        const float4* xb = reinterpret_cast<const float4*>(xt + (size_t)(m0 + 1) * 256);
        double a0 = 0.0, a1 = 0.0;
        #pragma unroll 8
        for (int c4 = 0; c4 < 64; ++c4) {
            float4 wv = wl4[c4 * 64 + lane];
            float4 v0 = xa[c4], v1 = xb[c4];
            a0 += (double)wv.x * v0.x + (double)wv.y * v0.y +
                  (double)wv.z * v0.z + (double)wv.w * v0.w;
            a1 += (double)wv.x * v1.x + (double)wv.y * v1.y +
                  (double)wv.z * v1.z + (double)wv.w * v1.w;
        }
        #pragma unroll
        for (int e = 0; e < 2; ++e) {
            double acc = e ? a1 : a0;
            double t = (acc - mn) * scale + bt;
            double s = t / (1.0 + exp(-t));          // SiLU
            double sq = s * s;                        // squash over 8-lane group
            sq += __shfl_xor(sq, 1);
            sq += __shfl_xor(sq, 2);
            sq += __shfl_xor(sq, 4);
            double f = (sq / (1.0 + sq)) / sqrt(sq + 1e-7);
            child_t[(size_t)(m0 + e) * 64 + o] = (float)(s * f);
        }
    }
}

// ---------------- Kernel C2: transpose conv weights to [tap][oc][c] ---------
__global__ void kC2(const float* __restrict__ ow, float* __restrict__ wt2) {
    int t = blockIdx.x * 256 + threadIdx.x;   // 18432
    int c = t & 255, oc = (t >> 8) & 7, tap = t >> 11;
    wt2[t] = ow[(oc * 256 + c) * 9 + tap];
}

// ---------------- Kernel B: 3x3 offset conv + tanh -> sampling grids --------
// 4 waves/block, 4 pixels/wave. lane = 4-channel chunk. taps 0..7 in LDS.
__global__ __launch_bounds__(256) void kB(const float* __restrict__ xt,
        const float* __restrict__ wt2, const float* __restrict__ ob,
        float* __restrict__ grids) {
    __shared__ float wl[16384];               // 8 taps x 8 oc x 256 c = 64 KB
    for (int i = threadIdx.x; i < 4096; i += 256)
        reinterpret_cast<float4*>(wl)[i] =
            reinterpret_cast<const float4*>(wt2)[i];
    __syncthreads();

    int wid = threadIdx.x >> 6, lane = threadIdx.x & 63;
    for (int p = 0; p < 4; ++p) {
        int m = (blockIdx.x * 4 + wid) * 4 + p;
        int b = m >> 10, hw = m & 1023;
        int yy = hw >> 5, xx = hw & 31;
        const float* xb = xt + (size_t)b * HW * 256;

        float acc[8] = {0.f, 0.f, 0.f, 0.f, 0.f, 0.f, 0.f, 0.f};
        #pragma unroll
        for (int tap = 0; tap < 9; ++tap) {
            int ky = tap / 3 - 1, kx = tap % 3 - 1;
            int yq = yy + ky, xq = xx + kx;
            if (yq < 0 || yq > Hd - 1 || xq < 0 || xq > Wd - 1) continue;
            float4 xv = *reinterpret_cast<const float4*>(
                xb + (size_t)(yq * Wd + xq) * 256 + lane * 4);
            #pragma unroll
            for (int oc = 0; oc < 8; ++oc) {
                float4 wv = (tap < 8)
                    ? *reinterpret_cast<const float4*>(wl + (tap * 8 + oc) * 256 + lane * 4)
                    : *reinterpret_cast<const float4*>(wt2 + (8 * 8 + oc) * 256 + lane * 4);
                acc[oc] += xv.x * wv.x + xv.y * wv.y + xv.z * wv.z + xv.w * wv.w;
            }
        }
        #pragma unroll
        for (int mk = 1; mk <= 32; mk <<= 1)
            #pragma unroll
            for (int oc = 0; oc < 8; ++oc)
                acc[oc] += __shfl_xor(acc[oc], mk);

        if (lane < 8) {
            double t = tanh((double)acc[lane] + (double)ob[lane]);
            int coord = lane & 1, si = lane >> 1;
            double base = coord ? (-1.0 + 2.0 * (double)yy / 31.0)
                                : (-1.0 + 2.0 * (double)xx / 31.0);
            grids[(size_t)m * 8 + si * 2 + coord] = (float)(base + t / 15.5);
        }
    }
}

// ---------------- Kernel C: reorder routing_W for coalesced float4 reads ----
// lane l <-> (n = l>>1, half = l&1); chunk j4 = o_loc*32 + d*2 + i4
// wt[j4*256 + l*4 + e] = W[n*1024 + half*512 + j4*4 + e]
__global__ void kC(const float* __restrict__ rw, float* __restrict__ wt) {
    int t = blockIdx.x * 256 + threadIdx.x;  // 32768
    int e = t & 3, l = (t >> 2) & 63, j4 = t >> 8;
    int n = l >> 1, half = l & 1;
    wt[t] = rw[n * 1024 + half * 512 + j4 * 4 + e];
}

// ---------------- Kernel D: bilinear sample + u_hat + dynamic routing -------
// 8 waves/block, 4 pixels/wave, grid 256 (1 block/CU). wt in 128 KB dyn LDS.
// lane <-> (n = lane>>1, half = lane&1). u_hat in regs u[4][16], ALL indices
// compile-time static (scratch-allocation paranoia, rule #20).
__global__ __launch_bounds__(512, 2) void kD(const float* __restrict__ child_t,
        const float* __restrict__ grids, const float* __restrict__ wt,
        float* __restrict__ out) {
    extern __shared__ float wl[];             // 32768 floats = 128 KB
    {
        const float4* src = reinterpret_cast<const float4*>(wt);
        float4* dst = reinterpret_cast<float4*>(wl);
        #pragma unroll
        for (int i = 0; i < 16; ++i) dst[threadIdx.x + i * 512] = src[threadIdx.x + i * 512];
    }
    __syncthreads();
    int wid = threadIdx.x >> 6, lane = threadIdx.x & 63;
    int n = lane >> 1, half = lane & 1;
    int si = n >> 3, ch = n & 7;
    int o_own = lane >> 4;                    // which o this lane outputs
    const float4* wl4 = reinterpret_cast<const float4*>(wl) + lane;

    #pragma unroll 1
    for (int p = 0; p < 4; ++p) {
        int m = (blockIdx.x * 8 + wid) * 4 + p;   // pixel
        int b = m >> 10, hw = m & 1023;

        // ---- bilinear sampling (align_corners=True, zeros padding), f32 ----
        float gx = grids[m * 8 + si * 2 + 0];
        float gy = grids[m * 8 + si * 2 + 1];
        float xf = (gx + 1.f) * 0.5f * 31.f;
        float yf = (gy + 1.f) * 0.5f * 31.f;
        float x0 = floorf(xf), y0 = floorf(yf);
        float wx1 = xf - x0, wx0 = 1.f - wx1;
        float wy1 = yf - y0, wy0 = 1.f - wy1;
        float sf[8] = {0.f, 0.f, 0.f, 0.f, 0.f, 0.f, 0.f, 0.f};
        const float* cb = child_t + (size_t)b * HW * 64 + ch * 8;
        #pragma unroll
        for (int cy = 0; cy < 2; ++cy) {
            float yq = y0 + (float)cy;
            bool vy = (yq >= 0.f) && (yq <= 31.f);
            float wy = cy ? wy1 : wy0;
            #pragma unroll
            for (int cx = 0; cx < 2; ++cx) {
                float xq = x0 + (float)cx;
                bool ok = vy && (xq >= 0.f) && (xq <= 31.f);
                if (!ok) continue;
                float w = wy * (cx ? wx1 : wx0);
                const float* cp = cb + (size_t)((int)yq * Wd + (int)xq) * 64;
                float4 v0 = *reinterpret_cast<const float4*>(cp);
                float4 v1 = *reinterpret_cast<const float4*>(cp + 4);
                sf[0] += w * v0.x; sf[1] += w * v0.y;
                sf[2] += w * v0.z; sf[3] += w * v0.w;
                sf[4] += w * v1.x; sf[5] += w * v1.y;
                sf[6] += w * v1.z; sf[7] += w * v1.w;
            }
        }

        // ---- u_hat = W[n] . samp : fully static o/d/i4 nest ----
        float u[4][16];
        #pragma unroll
        for (int o = 0; o < 4; ++o) {
            #pragma unroll
            for (int d = 0; d < 16; ++d) {
                float acc = 0.f;
                #pragma unroll
                for (int i4 = 0; i4 < 2; ++i4) {
                    float4 wv = wl4[(o * 32 + d * 2 + i4) * 64];
                    acc += wv.x * sf[i4 * 4 + 0] + wv.y * sf[i4 * 4 + 1] +
                           wv.z * sf[i4 * 4 + 2] + wv.w * sf[i4 * 4 + 3];
                }
                u[o][d] = acc;
            }
        }

        // ---- dynamic routing (3 iters); per-o transient vvo[16] ----
        float bl[4] = {0.f, 0.f, 0.f, 0.f};
        #pragma unroll
        for (int it = 0; it < 3; ++it) {
            float mx = fmaxf(fmaxf(bl[0], bl[1]), fmaxf(bl[2], bl[3]));
            mx = fmaxf(mx, __shfl_xor(mx, 1));
            float ex[4], ssum = 0.f;
            #pragma unroll
            for (int k = 0; k < 4; ++k) { ex[k] = expf(bl[k] - mx); ssum += ex[k]; }
            ssum += __shfl_xor(ssum, 1);
            float rs = 1.f / ssum;
            #pragma unroll
            for (int o = 0; o < 4; ++o) {
                float c = ex[o] * rs;
                float vvo[16];
                #pragma unroll
                for (int d = 0; d < 16; ++d) vvo[d] = c * u[o][d];
                #pragma unroll
                for (int mk = 2; mk <= 32; mk <<= 1)
                    #pragma unroll
                    for (int d = 0; d < 16; ++d)
                        vvo[d] += __shfl_xor(vvo[d], mk);
                float sq = 0.f;
                #pragma unroll
                for (int d = 0; d < 16; ++d) sq += vvo[d] * vvo[d];
                float f = (sq / (1.f + sq)) / sqrtf(sq + 1e-7f);
                if (it < 2) {
                    float agg = 0.f;
                    #pragma unroll
                    for (int d = 0; d < 16; ++d) agg += u[o][d] * (vvo[d] * f);
                    bl[o] += agg;
                } else if (o_own == o) {
                    // lane owns och = half*4 + o; writes d = (n&7)*2 + {0,1}
                    int och = half * 4 + o;
                    int d0 = (n & 7) * 2;
                    float* op = out + ((size_t)b * 128 + och * 16) * HW + hw;
                    op[(size_t)(d0 + 0) * HW] = vvo[d0 + 0] * f;
                    op[(size_t)(d0 + 1) * HW] = vvo[d0 + 1] * f;
                }
            }
        }
    }
}

extern "C" void kernel_launch(void* const* d_in, const int* in_sizes, int n_in,
                              void* d_out, int out_size, void* d_ws, size_t ws_size,
                              hipStream_t stream) {
    const float* x     = (const float*)d_in[0];
    const float* pw    = (const float*)d_in[1];
    const float* gamma = (const float*)d_in[2];
    const float* beta  = (const float*)d_in[3];
    const float* mean  = (const float*)d_in[4];
    const float* var   = (const float*)d_in[5];
    const float* ow    = (const float*)d_in[6];
    const float* ob    = (const float*)d_in[7];
    const float* rw    = (const float*)d_in[8];
    float* out = (float*)d_out;
    char* ws = (char*)d_ws;
    float* child_t = (float*)ws;                    // 8192*64*4 = 2 MiB
    float* grids   = (float*)(ws + 2097152);        // 8192*8*4  = 256 KiB
    float* wt      = (float*)(ws + 2359296);        // 32768*4   = 128 KiB
    float* xt      = (float*)(ws + 2490368);        // 8192*256*4 = 8 MiB
    float* wt2     = (float*)(ws + 10878976);       // 18432*4   = 72 KiB

    hipLaunchKernelGGL(kT, dim3(512), dim3(256), 0, stream, x, xt);
    hipLaunchKernelGGL(kC2, dim3(72), dim3(256), 0, stream, ow, wt2);
    hipLaunchKernelGGL(kC, dim3(128), dim3(256), 0, stream, rw, wt);
    hipLaunchKernelGGL(kA, dim3(512), dim3(256), 0, stream,
                       xt, pw, gamma, beta, mean, var, child_t);
    hipLaunchKernelGGL(kB, dim3(512), dim3(256), 0, stream, xt, wt2, ob, grids);
    hipLaunchKernelGGL(kD, dim3(256), dim3(512), 131072, stream,
                       child_t, grids, wt, out);
}

// Round 5
// 109.857 us; speedup vs baseline: 2.9471x; 2.6275x over previous
//
#include <hip/hip_runtime.h>
#include <math.h>

#define HW 1024
#define Hd 32
#define Wd 32
#define Bn 8
#define Cc 256

// ---------------- Kernel T: transpose x[b][c][hw] -> xt[b*1024+hw][c] -------
__global__ __launch_bounds__(256) void kT(const float* __restrict__ x,
                                          float* __restrict__ xt) {
    __shared__ float tile[64][65];
    int bid = blockIdx.x;                 // 8 b x 4 ct x 16 ht = 512
    int b = bid >> 6, ct = (bid >> 4) & 3, ht = bid & 15;
    int c0 = ct * 64, hw0 = ht * 64;
    int tr = threadIdx.x >> 6, tc = threadIdx.x & 63;
    const float* xb = x + ((size_t)b * 256 + c0) * 1024 + hw0;
    #pragma unroll
    for (int k = 0; k < 16; ++k) {
        int c = tr + k * 4;
        tile[c][tc] = xb[(size_t)c * 1024 + tc];
    }
    __syncthreads();
    float* xo = xt + ((size_t)b * 1024 + hw0) * 256 + c0;
    #pragma unroll
    for (int k = 0; k < 16; ++k) {
        int hwl = tr + k * 4;
        xo[(size_t)hwl * 256 + tc] = tile[tc][hwl];
    }
}

// ---------------- Kernel A: primary caps (1x1 conv + BN + SiLU + squash) ----
__global__ __launch_bounds__(256) void kA(const float* __restrict__ xt,
        const float* __restrict__ pw, const float* __restrict__ gamma,
        const float* __restrict__ beta, const float* __restrict__ mean,
        const float* __restrict__ var, float* __restrict__ child_t) {
    __shared__ float wl[16384];           // [c4][o][e] layout, 64 KB
    for (int i = threadIdx.x; i < 16384; i += 256) {
        int o = i >> 8, c = i & 255;
        wl[((c >> 2) * 64 + o) * 4 + (c & 3)] = pw[i];
    }
    __syncthreads();
    int wid = threadIdx.x >> 6, lane = threadIdx.x & 63;
    int o = lane;
    double scale = (double)gamma[o] / sqrt((double)var[o] + 1e-5);
    double mn = (double)mean[o], bt = (double)beta[o];
    const float4* wl4 = reinterpret_cast<const float4*>(wl);
    #pragma unroll
    for (int pp = 0; pp < 4; pp += 2) {   // 2 pixels share each weight pass
        int m0 = (blockIdx.x * 4 + wid) * 4 + pp;
        const float4* xa = reinterpret_cast<const float4*>(xt + (size_t)m0 * 256);
        const float4* xb = reinterpret_cast<const float4*>(xt + (size_t)(m0 + 1) * 256);
        double a0 = 0.0, a1 = 0.0;
        #pragma unroll 8
        for (int c4 = 0; c4 < 64; ++c4) {
            float4 wv = wl4[c4 * 64 + lane];
            float4 v0 = xa[c4], v1 = xb[c4];
            a0 += (double)wv.x * v0.x + (double)wv.y * v0.y +
                  (double)wv.z * v0.z + (double)wv.w * v0.w;
            a1 += (double)wv.x * v1.x + (double)wv.y * v1.y +
                  (double)wv.z * v1.z + (double)wv.w * v1.w;
        }
        #pragma unroll
        for (int e = 0; e < 2; ++e) {
            double acc = e ? a1 : a0;
            double t = (acc - mn) * scale + bt;
            double s = t / (1.0 + exp(-t));          // SiLU
            double sq = s * s;                        // squash over 8-lane group
            sq += __shfl_xor(sq, 1);
            sq += __shfl_xor(sq, 2);
            sq += __shfl_xor(sq, 4);
            double f = (sq / (1.0 + sq)) / sqrt(sq + 1e-7);
            child_t[(size_t)(m0 + e) * 64 + o] = (float)(s * f);
        }
    }
}

// ---------------- Kernel C2: transpose conv weights to [tap][oc][c] ---------
__global__ void kC2(const float* __restrict__ ow, float* __restrict__ wt2) {
    int t = blockIdx.x * 256 + threadIdx.x;   // 18432
    int c = t & 255, oc = (t >> 8) & 7, tap = t >> 11;
    wt2[t] = ow[(oc * 256 + c) * 9 + tap];
}

// ---------------- Kernel B: 3x3 offset conv + tanh -> sampling grids --------
__global__ __launch_bounds__(256) void kB(const float* __restrict__ xt,
        const float* __restrict__ wt2, const float* __restrict__ ob,
        float* __restrict__ grids) {
    __shared__ float wl[16384];               // 8 taps x 8 oc x 256 c = 64 KB
    for (int i = threadIdx.x; i < 4096; i += 256)
        reinterpret_cast<float4*>(wl)[i] =
            reinterpret_cast<const float4*>(wt2)[i];
    __syncthreads();

    int wid = threadIdx.x >> 6, lane = threadIdx.x & 63;
    for (int p = 0; p < 4; ++p) {
        int m = (blockIdx.x * 4 + wid) * 4 + p;
        int b = m >> 10, hw = m & 1023;
        int yy = hw >> 5, xx = hw & 31;
        const float* xb = xt + (size_t)b * HW * 256;

        float acc[8] = {0.f, 0.f, 0.f, 0.f, 0.f, 0.f, 0.f, 0.f};
        #pragma unroll
        for (int tap = 0; tap < 9; ++tap) {
            int ky = tap / 3 - 1, kx = tap % 3 - 1;
            int yq = yy + ky, xq = xx + kx;
            if (yq < 0 || yq > Hd - 1 || xq < 0 || xq > Wd - 1) continue;
            float4 xv = *reinterpret_cast<const float4*>(
                xb + (size_t)(yq * Wd + xq) * 256 + lane * 4);
            #pragma unroll
            for (int oc = 0; oc < 8; ++oc) {
                float4 wv = (tap < 8)
                    ? *reinterpret_cast<const float4*>(wl + (tap * 8 + oc) * 256 + lane * 4)
                    : *reinterpret_cast<const float4*>(wt2 + (8 * 8 + oc) * 256 + lane * 4);
                acc[oc] += xv.x * wv.x + xv.y * wv.y + xv.z * wv.z + xv.w * wv.w;
            }
        }
        #pragma unroll
        for (int mk = 1; mk <= 32; mk <<= 1)
            #pragma unroll
            for (int oc = 0; oc < 8; ++oc)
                acc[oc] += __shfl_xor(acc[oc], mk);

        if (lane < 8) {
            double t = tanh((double)acc[lane] + (double)ob[lane]);
            int coord = lane & 1, si = lane >> 1;
            double base = coord ? (-1.0 + 2.0 * (double)yy / 31.0)
                                : (-1.0 + 2.0 * (double)xx / 31.0);
            grids[(size_t)m * 8 + si * 2 + coord] = (float)(base + t / 15.5);
        }
    }
}

// ---------------- Kernel C: reorder routing_W for coalesced float4 reads ----
// lane l <-> (n = l>>1, half = l&1); chunk j4 = o_loc*32 + d*2 + i4
// wt[j4*256 + l*4 + e] = W[n*1024 + half*512 + j4*4 + e]
__global__ void kC(const float* __restrict__ rw, float* __restrict__ wt) {
    int t = blockIdx.x * 256 + threadIdx.x;  // 32768
    int e = t & 3, l = (t >> 2) & 63, j4 = t >> 8;
    int n = l >> 1, half = l & 1;
    wt[t] = rw[n * 1024 + half * 512 + j4 * 4 + e];
}

// ---------------- Kernel D v3: sample + u_hat + routing ---------------------
// 2048 blocks x 256 thr, 1 pixel/wave. Weights read from L2 (no LDS staging).
// lane <-> (n = lane>>1, half = lane&1); u[4][16] in regs (all literal idx).
// Routing s-sum: recursive-halving reduce-scatter (16 shfl/o) + LDS v-bcast.
__global__ __launch_bounds__(256, 2) void kD(const float* __restrict__ child_t,
        const float* __restrict__ grids, const float* __restrict__ wt,
        float* __restrict__ out) {
    __shared__ float vsh[4][8][16];           // per-wave v broadcast, 2 KB
    int wid = threadIdx.x >> 6, lane = threadIdx.x & 63;
    int m = blockIdx.x * 4 + wid;             // pixel
    int b = m >> 10, hw = m & 1023;
    int n = lane >> 1, half = lane & 1;
    int si = n >> 3, ch = n & 7;
    // d-slot owned after reduce-scatter
    int dsl = (n & 1) * 8 + ((n >> 1) & 1) * 4 + ((n >> 2) & 1) * 2 + ((n >> 3) & 1);

    // ---- bilinear sampling (align_corners=True, zeros padding), f32 ----
    float gx = grids[m * 8 + si * 2 + 0];
    float gy = grids[m * 8 + si * 2 + 1];
    float xf = (gx + 1.f) * 0.5f * 31.f;
    float yf = (gy + 1.f) * 0.5f * 31.f;
    float x0 = floorf(xf), y0 = floorf(yf);
    float wx1 = xf - x0, wx0 = 1.f - wx1;
    float wy1 = yf - y0, wy0 = 1.f - wy1;
    float sf[8] = {0.f, 0.f, 0.f, 0.f, 0.f, 0.f, 0.f, 0.f};
    const float* cb = child_t + (size_t)b * HW * 64 + ch * 8;
    #pragma unroll
    for (int cy = 0; cy < 2; ++cy) {
        float yq = y0 + (float)cy;
        bool vy = (yq >= 0.f) && (yq <= 31.f);
        float wy = cy ? wy1 : wy0;
        #pragma unroll
        for (int cx = 0; cx < 2; ++cx) {
            float xq = x0 + (float)cx;
            bool ok = vy && (xq >= 0.f) && (xq <= 31.f);
            if (!ok) continue;
            float w = wy * (cx ? wx1 : wx0);
            const float* cp = cb + (size_t)((int)yq * Wd + (int)xq) * 64;
            float4 v0 = *reinterpret_cast<const float4*>(cp);
            float4 v1 = *reinterpret_cast<const float4*>(cp + 4);
            sf[0] += w * v0.x; sf[1] += w * v0.y;
            sf[2] += w * v0.z; sf[3] += w * v0.w;
            sf[4] += w * v1.x; sf[5] += w * v1.y;
            sf[6] += w * v1.z; sf[7] += w * v1.w;
        }
    }

    // ---- u_hat = W[n] . samp : weights streamed from L2, coalesced ----
    float u[4][16];
    const float4* wt4 = reinterpret_cast<const float4*>(wt) + lane;
    #pragma unroll
    for (int o = 0; o < 4; ++o) {
        #pragma unroll
        for (int d = 0; d < 16; ++d) {
            float4 w0 = wt4[(o * 32 + d * 2 + 0) * 64];
            float4 w1 = wt4[(o * 32 + d * 2 + 1) * 64];
            u[o][d] = w0.x * sf[0] + w0.y * sf[1] + w0.z * sf[2] + w0.w * sf[3]
                    + w1.x * sf[4] + w1.y * sf[5] + w1.z * sf[6] + w1.w * sf[7];
        }
    }

    // ---- dynamic routing (3 iters) ----
    float bl[4] = {0.f, 0.f, 0.f, 0.f};
    #pragma unroll
    for (int it = 0; it < 3; ++it) {
        // softmax over 8 parents: local 4 + lane-pair (xor 1)
        float mx = fmaxf(fmaxf(bl[0], bl[1]), fmaxf(bl[2], bl[3]));
        mx = fmaxf(mx, __shfl_xor(mx, 1));
        float ex[4], ssum = 0.f;
        #pragma unroll
        for (int k = 0; k < 4; ++k) { ex[k] = expf(bl[k] - mx); ssum += ex[k]; }
        ssum += __shfl_xor(ssum, 1);
        float rs = 1.f / ssum;

        float sval[4];
        #pragma unroll
        for (int o = 0; o < 4; ++o) {
            float cc = ex[o] * rs;
            // reduce-scatter over n (recursive halving): 8+4+2+1+1 shuffles
            float y[8];
            #pragma unroll
            for (int d = 0; d < 8; ++d) {
                float t = (n & 1) ? cc * u[o][d] : cc * u[o][d + 8]; // send
                float k = (n & 1) ? cc * u[o][d + 8] : cc * u[o][d]; // keep
                y[d] = k + __shfl_xor(t, 2);
            }
            float z[4];
            #pragma unroll
            for (int d = 0; d < 4; ++d) {
                float t = (n & 2) ? y[d] : y[d + 4];
                float k = (n & 2) ? y[d + 4] : y[d];
                z[d] = k + __shfl_xor(t, 4);
            }
            float w2[2];
            #pragma unroll
            for (int d = 0; d < 2; ++d) {
                float t = (n & 4) ? z[d] : z[d + 2];
                float k = (n & 4) ? z[d + 2] : z[d];
                w2[d] = k + __shfl_xor(t, 8);
            }
            float t4 = (n & 8) ? w2[0] : w2[1];
            float k4 = (n & 8) ? w2[1] : w2[0];
            float s1 = k4 + __shfl_xor(t4, 16);
            s1 += __shfl_xor(s1, 32);                 // merge bit4 halves
            sval[o] = s1;
        }
        // squash: sq_o = sum_d s^2 over the 16 d-owners (n-bits 0..3)
        #pragma unroll
        for (int o = 0; o < 4; ++o) {
            float q = sval[o] * sval[o];
            q += __shfl_xor(q, 2);
            q += __shfl_xor(q, 4);
            q += __shfl_xor(q, 8);
            q += __shfl_xor(q, 16);
            float f = (q / (1.f + q)) / sqrtf(q + 1e-7f);
            if ((lane & 32) == 0)                     // one writer per (o,d)
                vsh[wid][half * 4 + o][dsl] = sval[o] * f;
        }
        if (it < 2) {
            // agreement: b[n][o] += sum_d u[n][o][d] * v[o][d]  (v from LDS)
            #pragma unroll
            for (int o = 0; o < 4; ++o) {
                const float4* vr = reinterpret_cast<const float4*>(
                    &vsh[wid][half * 4 + o][0]);
                float4 v0 = vr[0], v1 = vr[1], v2 = vr[2], v3 = vr[3];
                float agg = u[o][0] * v0.x + u[o][1] * v0.y +
                            u[o][2] * v0.z + u[o][3] * v0.w +
                            u[o][4] * v1.x + u[o][5] * v1.y +
                            u[o][6] * v1.z + u[o][7] * v1.w +
                            u[o][8] * v2.x + u[o][9] * v2.y +
                            u[o][10] * v2.z + u[o][11] * v2.w +
                            u[o][12] * v3.x + u[o][13] * v3.y +
                            u[o][14] * v3.z + u[o][15] * v3.w;
                bl[o] += agg;
            }
        } else {
            // output: lane writes 2 dwords of out[b][och][d][hw]
            int o_own = lane >> 4;                    // n-bits 3..4
            int och = half * 4 + o_own;
            int d0 = (n & 7) * 2;
            float va = vsh[wid][och][d0 + 0];
            float vb = vsh[wid][och][d0 + 1];
            float* op = out + ((size_t)b * 128 + och * 16) * HW + hw;
            op[(size_t)(d0 + 0) * HW] = va;
            op[(size_t)(d0 + 1) * HW] = vb;
        }
    }
}

extern "C" void kernel_launch(void* const* d_in, const int* in_sizes, int n_in,
                              void* d_out, int out_size, void* d_ws, size_t ws_size,
                              hipStream_t stream) {
    const float* x     = (const float*)d_in[0];
    const float* pw    = (const float*)d_in[1];
    const float* gamma = (const float*)d_in[2];
    const float* beta  = (const float*)d_in[3];
    const float* mean  = (const float*)d_in[4];
    const float* var   = (const float*)d_in[5];
    const float* ow    = (const float*)d_in[6];
    const float* ob    = (const float*)d_in[7];
    const float* rw    = (const float*)d_in[8];
    float* out = (float*)d_out;
    char* ws = (char*)d_ws;
    float* child_t = (float*)ws;                    // 8192*64*4 = 2 MiB
    float* grids   = (float*)(ws + 2097152);        // 8192*8*4  = 256 KiB
    float* wt      = (float*)(ws + 2359296);        // 32768*4   = 128 KiB
    float* xt      = (float*)(ws + 2490368);        // 8192*256*4 = 8 MiB
    float* wt2     = (float*)(ws + 10878976);       // 18432*4   = 72 KiB

    hipLaunchKernelGGL(kT, dim3(512), dim3(256), 0, stream, x, xt);
    hipLaunchKernelGGL(kC2, dim3(72), dim3(256), 0, stream, ow, wt2);
    hipLaunchKernelGGL(kC, dim3(128), dim3(256), 0, stream, rw, wt);
    hipLaunchKernelGGL(kA, dim3(512), dim3(256), 0, stream,
                       xt, pw, gamma, beta, mean, var, child_t);
    hipLaunchKernelGGL(kB, dim3(512), dim3(256), 0, stream, xt, wt2, ob, grids);
    hipLaunchKernelGGL(kD, dim3(2048), dim3(256), 0, stream,
                       child_t, grids, wt, out);
}